// Round 5
// baseline (245.396 us; speedup 1.0000x reference)
//
#include <hip/hip_runtime.h>
#include <hip/hip_bf16.h>
#include <stdint.h>

// DelayedDMD: BS=64, D=256, M=512, m_prox=10 (fixed). A-orientation algebra:
//   G1 = Y1@Y1^T (sym), G21 = Y2@Y1^T
//   q = P^T y1, Piy1 = P y1, k = 1/(1+y1.Piy1)
//   w = y1 - G1 q ; u = G21 q
//   negE = -(P@G1 + k y1 w^T)  [bf16]
//   V'   = G21@P^T + k (y2-u) y1^T  [bf16]
//   x10: A <- A + V' + A@negE^T  (fp32 ACC in regs, bf16 A-shadow via LDS)
//   out1 = A_10 ; out2 = P - k Piy1 q^T
// 4 launches: prep1 (convY + Piy1/q/k), prep2 (G-gemms + convP/out2),
//             gemmEV (E/V' with in-block rank-1), iterk (persistent 10-step).

#define BSZ 64
#define DD 256
#define MM 512

typedef __attribute__((ext_vector_type(8))) short short8;
typedef __attribute__((ext_vector_type(4))) float f32x4;

__device__ __forceinline__ unsigned short f2b(float f) {
    unsigned int u = __float_as_uint(f);
    unsigned int r = (u + 0x7fffu + ((u >> 16) & 1u)) >> 16;
    return (unsigned short)r;
}
__device__ __forceinline__ float b2f(unsigned short s) {
    return __uint_as_float(((unsigned int)s) << 16);
}

#define GLDS16(gp, lp)                                                                   \
    __builtin_amdgcn_global_load_lds((const __attribute__((address_space(1))) void*)(gp),\
                                     (__attribute__((address_space(3))) void*)(lp),      \
                                     16, 0, 0)

// vec per batch (768 f): [0,256) Piy1 | [256,512) q | [512] k

// ---------------- L1: convY (blocks 0..2047) + Piy1/k, q (blocks 2048..2175) ----
__global__ __launch_bounds__(256)
void prep1(const float* __restrict__ Y1, const float* __restrict__ Y2,
           const float* __restrict__ y1, const float* __restrict__ P,
           unsigned short* __restrict__ Y1b, unsigned short* __restrict__ Y2b,
           float* __restrict__ vec)
{
    const int blk = blockIdx.x, t = threadIdx.x;
    if (blk < 2048) {
        // bf16 convert of Y1 ++ Y2 (4,194,304 float4 groups total)
#pragma unroll
        for (int i = 0; i < 8; ++i) {
            const long g4 = (long)blk * 2048 + i * 256 + t;
            const float* s; unsigned short* d; long off;
            if (g4 < 2097152) { s = Y1; d = Y1b; off = g4 * 4; }
            else              { s = Y2; d = Y2b; off = (g4 - 2097152) * 4; }
            float4 v = *(const float4*)(s + off);
            ushort4 o;
            o.x = f2b(v.x); o.y = f2b(v.y); o.z = f2b(v.z); o.w = f2b(v.w);
            *(ushort4*)(d + off) = o;
        }
        return;
    }
    const int c = blk - 2048, b = c >> 1;
    const float* Pb = P + (long)b * DD * DD;
    float* vb = vec + (long)b * 768;
    __shared__ float sy1[DD];
    __shared__ float red[DD];
    __shared__ float pi[DD];
    sy1[t] = y1[b * DD + t];
    __syncthreads();
    if (c & 1) {
        // q[j] = sum_l y1[l] P[l][j] (coalesced across j)
        float s = 0.f;
        for (int l = 0; l < DD; ++l) s += sy1[l] * Pb[(long)l * DD + t];
        vb[256 + t] = s;
    } else {
        // Piy1 rows + k
        const int wv = t >> 6, ln = t & 63;
        for (int rr = 0; rr < 64; ++rr) {
            const int r = wv * 64 + rr;
            float s = 0.f;
#pragma unroll
            for (int cc = 0; cc < 4; ++cc) s += Pb[(long)r * DD + cc * 64 + ln] * sy1[cc * 64 + ln];
            for (int o = 32; o; o >>= 1) s += __shfl_down(s, o, 64);
            if (ln == 0) { vb[r] = s; pi[r] = s; }
        }
        __syncthreads();
        red[t] = sy1[t] * pi[t];
        __syncthreads();
        for (int s2 = 128; s2; s2 >>= 1) { if (t < s2) red[t] += red[t + s2]; __syncthreads(); }
        if (t == 0) vb[512] = 1.0f / (1.0f + red[0]);
    }
}

// ---------------- L2: G-gemms (blocks 0..511) + convP/out2 (512..767) ----------------
__global__ __launch_bounds__(256)
void prep2(const unsigned short* __restrict__ Y1b, const unsigned short* __restrict__ Y2b,
           const float* __restrict__ P, const float* __restrict__ vec,
           unsigned short* __restrict__ G1b, unsigned short* __restrict__ G21b,
           unsigned short* __restrict__ Pb, float* __restrict__ out2)
{
    __shared__ __align__(16) unsigned short As[128 * 32];
    __shared__ __align__(16) unsigned short Bs[128 * 32];
    const int blk = blockIdx.x, t = threadIdx.x;
    if (blk < 512) {
        const int quad = blk & 3, z = blk >> 2, sel = z >> 6, b = z & 63;
        const int i0 = (quad >> 1) * 128, j0 = (quad & 1) * 128;
        const unsigned short* Ab = (sel ? Y2b : Y1b) + (long)b * DD * MM;
        const unsigned short* Bb = Y1b + (long)b * DD * MM;
        unsigned short* Ob = (sel ? G21b : G1b) + (long)b * DD * DD;
        const int wv = t >> 6, ln = t & 63;
        const int lr = ln & 15, qd = ln >> 4;
        const int mh = (wv >> 1) * 64, nh = (wv & 1) * 64;
        const int g0 = wv * 64 + ln, g1 = 256 + wv * 64 + ln;
        const int r0g = g0 >> 2, k0g = (g0 & 3) * 8;
        const int r1g = g1 >> 2, k1g = (g1 & 3) * 8;
        f32x4 acc[4][4] = {};
        for (int kc = 0; kc < MM; kc += 32) {
            GLDS16(Ab + (long)(i0 + r0g) * MM + kc + k0g, As + g0 * 8);
            GLDS16(Ab + (long)(i0 + r1g) * MM + kc + k1g, As + g1 * 8);
            GLDS16(Bb + (long)(j0 + r0g) * MM + kc + k0g, Bs + g0 * 8);
            GLDS16(Bb + (long)(j0 + r1g) * MM + kc + k1g, Bs + g1 * 8);
            __syncthreads();
            short8 af[4], bfr[4];
#pragma unroll
            for (int mt = 0; mt < 4; ++mt)
                af[mt] = *(const short8*)(As + (mh + mt * 16 + lr) * 32 + qd * 8);
#pragma unroll
            for (int nt = 0; nt < 4; ++nt)
                bfr[nt] = *(const short8*)(Bs + (nh + nt * 16 + lr) * 32 + qd * 8);
#pragma unroll
            for (int mt = 0; mt < 4; ++mt)
#pragma unroll
                for (int nt = 0; nt < 4; ++nt)
                    acc[mt][nt] = __builtin_amdgcn_mfma_f32_16x16x32_bf16(
                        af[mt], bfr[nt], acc[mt][nt], 0, 0, 0);
            __syncthreads();
        }
#pragma unroll
        for (int mt = 0; mt < 4; ++mt)
#pragma unroll
            for (int nt = 0; nt < 4; ++nt) {
                const int gr0 = i0 + mh + mt * 16 + qd * 4;
                const int gc  = j0 + nh + nt * 16 + lr;
#pragma unroll
                for (int r = 0; r < 4; ++r)
                    Ob[(long)(gr0 + r) * DD + gc] = f2b(acc[mt][nt][r]);
            }
        return;
    }
    // convP strip: Pb = bf16(P), out2 = P - k Piy1 q^T
    const int c = blk - 512, b = c >> 2, rs = (c & 3) * 64;
    const long base = (long)b * DD * DD;
    const float* vb = vec + (long)b * 768;
    const float kk = vb[512];
#pragma unroll 4
    for (int i = 0; i < 16; ++i) {
        const int idx = rs * DD + (i * 256 + t) * 4;
        const int row = idx >> 8, col = idx & 255;
        const float kPi = kk * vb[row];
        float4 p = *(const float4*)(P + base + idx);
        ushort4 o;
        o.x = f2b(p.x); o.y = f2b(p.y); o.z = f2b(p.z); o.w = f2b(p.w);
        *(ushort4*)(Pb + base + idx) = o;
        float4 q = *(const float4*)(vb + 256 + col);
        float4 rr;
        rr.x = p.x - kPi * q.x; rr.y = p.y - kPi * q.y;
        rr.z = p.z - kPi * q.z; rr.w = p.w - kPi * q.w;
        *(float4*)(out2 + base + idx) = rr;
    }
}

// ---------------- L3: negE (z<64) / V' (z>=64) with in-block rank-1 ----------------
__global__ __launch_bounds__(256)
void gemmEV(const unsigned short* __restrict__ Pb, const unsigned short* __restrict__ G1b,
            const unsigned short* __restrict__ G21b,
            const float* __restrict__ y1g, const float* __restrict__ y2g,
            const float* __restrict__ vec,
            unsigned short* __restrict__ Enb, unsigned short* __restrict__ Vpb)
{
    __shared__ __align__(16) unsigned short As[128 * 32];
    __shared__ __align__(16) unsigned short Bs[128 * 32];
    __shared__ float qs[DD], s1[DD], s2[DD];
    const int z = blockIdx.z, sel = z >> 6, b = z & 63;
    const int i0 = blockIdx.y * 128, j0 = blockIdx.x * 128;
    const unsigned short* Ab = (sel ? G21b : Pb) + (long)b * DD * DD;
    const unsigned short* Bb = (sel ? Pb : G1b) + (long)b * DD * DD;
    unsigned short* Ob = (sel ? Vpb : Enb) + (long)b * DD * DD;
    const float* vb = vec + (long)b * 768;
    const int t = threadIdx.x, wv = t >> 6, ln = t & 63;
    const int lr = ln & 15, qd = ln >> 4;
    const int mh = (wv >> 1) * 64, nh = (wv & 1) * 64;
    const int g0 = wv * 64 + ln, g1 = 256 + wv * 64 + ln;
    const int r0g = g0 >> 2, k0g = (g0 & 3) * 8;
    const int r1g = g1 >> 2, k1g = (g1 & 3) * 8;

    qs[t] = vb[256 + t];
    s1[t] = y1g[b * DD + t];
    s2[t] = y2g[b * DD + t];

    f32x4 acc[4][4] = {};
    float dot[4] = {0.f, 0.f, 0.f, 0.f};   // sel0: G1q partial per nt; sel1: G21q per mt

    for (int kc = 0; kc < DD; kc += 32) {
        GLDS16(Ab + (long)(i0 + r0g) * DD + kc + k0g, As + g0 * 8);
        GLDS16(Ab + (long)(i0 + r1g) * DD + kc + k1g, As + g1 * 8);
        GLDS16(Bb + (long)(j0 + r0g) * DD + kc + k0g, Bs + g0 * 8);
        GLDS16(Bb + (long)(j0 + r1g) * DD + kc + k1g, Bs + g1 * 8);
        __syncthreads();
        short8 af[4], bfr[4];
#pragma unroll
        for (int mt = 0; mt < 4; ++mt)
            af[mt] = *(const short8*)(As + (mh + mt * 16 + lr) * 32 + qd * 8);
#pragma unroll
        for (int nt = 0; nt < 4; ++nt)
            bfr[nt] = *(const short8*)(Bs + (nh + nt * 16 + lr) * 32 + qd * 8);
        // rank-1 partial dots with q (fp32 accum, bf16 matrix)
        const float4 qa = *(const float4*)(qs + kc + qd * 8);
        const float4 qb = *(const float4*)(qs + kc + qd * 8 + 4);
        const float qf[8] = {qa.x, qa.y, qa.z, qa.w, qb.x, qb.y, qb.z, qb.w};
        if (!sel) {
#pragma unroll
            for (int nt = 0; nt < 4; ++nt)
#pragma unroll
                for (int j = 0; j < 8; ++j)
                    dot[nt] += b2f((unsigned short)bfr[nt][j]) * qf[j];
        } else {
#pragma unroll
            for (int mt = 0; mt < 4; ++mt)
#pragma unroll
                for (int j = 0; j < 8; ++j)
                    dot[mt] += b2f((unsigned short)af[mt][j]) * qf[j];
        }
#pragma unroll
        for (int mt = 0; mt < 4; ++mt)
#pragma unroll
            for (int nt = 0; nt < 4; ++nt)
                acc[mt][nt] = __builtin_amdgcn_mfma_f32_16x16x32_bf16(
                    af[mt], bfr[nt], acc[mt][nt], 0, 0, 0);
        __syncthreads();
    }
    // complete dots across qd quads (lanes lr, lr+16, lr+32, lr+48)
#pragma unroll
    for (int i = 0; i < 4; ++i) {
        dot[i] += __shfl_xor(dot[i], 16, 64);
        dot[i] += __shfl_xor(dot[i], 32, 64);
    }
    const float kk = vb[512];
#pragma unroll
    for (int mt = 0; mt < 4; ++mt) {
#pragma unroll
        for (int nt = 0; nt < 4; ++nt) {
            const int gr0 = i0 + mh + mt * 16 + qd * 4;
            const int gc  = j0 + nh + nt * 16 + lr;
            if (!sel) {
                // negE = -(acc + (k y1[row]) * w[col]), w[col] = y1[col] - G1q[col]
                const float cw = s1[gc] - dot[nt];
#pragma unroll
                for (int r = 0; r < 4; ++r) {
                    const float rv = kk * s1[gr0 + r];
                    Ob[(long)(gr0 + r) * DD + gc] = f2b(-(acc[mt][nt][r] + rv * cw));
                }
            } else {
                // V' = acc + (k (y2[row]-u[row])) * y1[col], u[row] = G21q[row]
                const float cv = s1[gc];
#pragma unroll
                for (int r = 0; r < 4; ++r) {
                    const float uv = __shfl(dot[mt], qd * 4 + r, 64);
                    const float rv = kk * (s2[gr0 + r] - uv);
                    Ob[(long)(gr0 + r) * DD + gc] = f2b(acc[mt][nt][r] + rv * cv);
                }
            }
        }
    }
}

// ---------------- L4: persistent 10-step iterate, XOR-swizzled LDS ----------------
// grid (8,64): 32-row strips, 2 WGs/CU. Wave wv owns cols [wv*64, wv*64+64).
#define SWZ(row) (((row) ^ ((row) >> 3)) & 7)
__global__ __launch_bounds__(256, 2)
void iterk(const float* __restrict__ A_start, const unsigned short* __restrict__ Enb,
           const unsigned short* __restrict__ Vpb, float* __restrict__ out1)
{
    __shared__ __align__(16) unsigned short Ash[32 * 256];
    const int b = blockIdx.y, r0 = blockIdx.x * 32;
    const long base = (long)b * DD * DD;
    const float* Ab = A_start + base;
    const unsigned short* Eb = Enb + base;
    const unsigned short* Vb = Vpb + base;
    float* Ob = out1 + base;
    const int t = threadIdx.x, wv = t >> 6, ln = t & 63;
    const int lr = ln & 15, qd = ln >> 4;

    f32x4 acc[2][4], vv[2][4];
    short8 ef[4][8];

#pragma unroll
    for (int mt = 0; mt < 2; ++mt)
#pragma unroll
        for (int j = 0; j < 4; ++j) {
            const int col = wv * 64 + j * 16 + lr;
            const int rowb = r0 + mt * 16 + qd * 4;
#pragma unroll
            for (int r = 0; r < 4; ++r) {
                const long o = (long)(rowb + r) * DD + col;
                acc[mt][j][r] = Ab[o];
                vv[mt][j][r]  = b2f(Vb[o]);
            }
        }
#pragma unroll
    for (int j = 0; j < 4; ++j) {
        const int n = wv * 64 + j * 16 + lr;
#pragma unroll
        for (int kc = 0; kc < 8; ++kc)
            ef[j][kc] = *(const short8*)(Eb + (long)n * DD + kc * 32 + qd * 8);
    }

#pragma unroll 1
    for (int s = 0; s < 10; ++s) {
        const int cgb = wv * 8 + (lr >> 3), cb = lr & 7;
#pragma unroll
        for (int mt = 0; mt < 2; ++mt)
#pragma unroll
            for (int j = 0; j < 4; ++j) {
#pragma unroll
                for (int r = 0; r < 4; ++r) {
                    const int lrow = mt * 16 + qd * 4 + r;
                    const int cg = (cgb + j * 2) ^ SWZ(lrow);
                    Ash[lrow * 256 + cg * 8 + cb] = f2b(acc[mt][j][r]);
                }
                acc[mt][j] += vv[mt][j];
            }
        __syncthreads();
#pragma unroll
        for (int kc = 0; kc < 8; ++kc) {
            short8 af[2];
#pragma unroll
            for (int mt = 0; mt < 2; ++mt) {
                const int row = mt * 16 + lr;
                const int cg = (kc * 4 + qd) ^ SWZ(row);
                af[mt] = *(const short8*)(Ash + row * 256 + cg * 8);
            }
#pragma unroll
            for (int mt = 0; mt < 2; ++mt)
#pragma unroll
                for (int j = 0; j < 4; ++j)
                    acc[mt][j] = __builtin_amdgcn_mfma_f32_16x16x32_bf16(
                        af[mt], ef[j][kc], acc[mt][j], 0, 0, 0);
        }
        __syncthreads();
    }

#pragma unroll
    for (int mt = 0; mt < 2; ++mt)
#pragma unroll
        for (int j = 0; j < 4; ++j) {
            const int col = wv * 64 + j * 16 + lr;
            const int rowb = r0 + mt * 16 + qd * 4;
#pragma unroll
            for (int r = 0; r < 4; ++r)
                Ob[(long)(rowb + r) * DD + col] = acc[mt][j][r];
        }
}

extern "C" void kernel_launch(void* const* d_in, const int* in_sizes, int n_in,
                              void* d_out, int out_size, void* d_ws, size_t ws_size,
                              hipStream_t stream)
{
    const float* A_start = (const float*)d_in[0];
    const float* Y1      = (const float*)d_in[1];
    const float* Y2      = (const float*)d_in[2];
    const float* y1      = (const float*)d_in[3];
    const float* y2      = (const float*)d_in[4];
    const float* P       = (const float*)d_in[5];

    const long EL2 = (long)BSZ * DD * DD;   // 4,194,304

    float* out1 = (float*)d_out;
    float* out2 = out1 + EL2;
    unsigned short* Y1b = (unsigned short*)out1;    // dead before iterk writes out1

    char* w8 = (char*)d_ws;                          // 42.2 MB used
    unsigned short* Pb   = (unsigned short*)(w8);                 // 8MB
    unsigned short* G1b  = (unsigned short*)(w8 + 8388608);       // 8MB
    unsigned short* G21b = (unsigned short*)(w8 + 16777216);      // 8MB
    unsigned short* Y2b  = (unsigned short*)(w8 + 25165824);      // 8MB, dead after prep2
    unsigned short* Enb  = (unsigned short*)(w8 + 25165824);      //   -> negE (8MB)
    unsigned short* Vpb  = (unsigned short*)(w8 + 33554432);      // 8MB
    float*          vec  = (float*)(w8 + 41943040);               // 64*768*4

    const dim3 blk(256);

    prep1<<<2176, blk, 0, stream>>>(Y1, Y2, y1, P, Y1b, Y2b, vec);
    prep2<<<768, blk, 0, stream>>>(Y1b, Y2b, P, vec, G1b, G21b, Pb, out2);
    gemmEV<<<dim3(2, 2, 128), blk, 0, stream>>>(Pb, G1b, G21b, y1, y2, vec, Enb, Vpb);
    iterk<<<dim3(8, 64), blk, 0, stream>>>(A_start, Enb, Vpb, out1);
}

// Round 6
// 218.035 us; speedup vs baseline: 1.1255x; 1.1255x over previous
//
#include <hip/hip_runtime.h>
#include <hip/hip_bf16.h>
#include <stdint.h>

// DelayedDMD: BS=64, D=256, M=512, m_prox=10 (fixed). A-orientation algebra:
//   G1 = Y1@Y1^T (sym), G21 = Y2@Y1^T
//   q = P^T y1, Piy1 = P y1, k = 1/(1+y1.Piy1)
//   w = y1 - G1 q ; u = G21 q
//   negE = -(P@G1 + k y1 w^T)  [bf16]
//   V'   = G21@P^T + k (y2-u) y1^T  [bf16]
//   x10: A <- A + V' + A@negE^T  (fp32 ACC in regs, bf16 A-shadow via LDS)
//   out1 = A_10 ; out2 = P - k Piy1 q^T
// 4 launches:
//   L1 prep1 : P-conv + Piy1 + q-partials (single pass over P)
//   L2 prep2 : G-gemms (fp32 Y staged w/ in-register bf16 convert) + q/k finalize
//   L3 gemmEV: negE/V' gemms w/ in-block rank-1 epilogue + out2 tail blocks
//   L4 iterk : persistent 10-step iterate (XOR-swizzled LDS, 2 WG/CU)

#define BSZ 64
#define DD 256
#define MM 512

typedef __attribute__((ext_vector_type(8))) short short8;
typedef __attribute__((ext_vector_type(4))) float f32x4;

__device__ __forceinline__ unsigned short f2b(float f) {
    unsigned int u = __float_as_uint(f);
    unsigned int r = (u + 0x7fffu + ((u >> 16) & 1u)) >> 16;
    return (unsigned short)r;
}
__device__ __forceinline__ float b2f(unsigned short s) {
    return __uint_as_float(((unsigned int)s) << 16);
}

// vec per batch (768 f): [0,256) Piy1 | [256,512) q | [512] k

// ---------------- L1: P-conv + Piy1 + q-partials (256 blocks, 4/batch) ----------------
__global__ __launch_bounds__(256)
void prep1(const float* __restrict__ P, const float* __restrict__ y1g,
           unsigned short* __restrict__ Pb, float* __restrict__ vec,
           float* __restrict__ qpart)
{
    const int blk = blockIdx.x, t = threadIdx.x;
    const int b = blk >> 2, rs = (blk & 3) * 64;
    const long base = (long)b * DD * DD;
    const int wv = t >> 6, ln = t & 63;
    __shared__ float sy1[DD];
    __shared__ float qsh[4][DD];
    sy1[t] = y1g[b * DD + t];
    __syncthreads();
    const int col4 = ln * 4;
    const float4 yv = *(const float4*)(sy1 + col4);
    float ql0 = 0.f, ql1 = 0.f, ql2 = 0.f, ql3 = 0.f;
#pragma unroll
    for (int i = 0; i < 16; ++i) {
        const int row = rs + i * 4 + wv;          // all 64 lanes of wave share this row
        const long o = base + (long)row * DD + col4;
        float4 p = *(const float4*)(P + o);
        ushort4 u;
        u.x = f2b(p.x); u.y = f2b(p.y); u.z = f2b(p.z); u.w = f2b(p.w);
        *(ushort4*)(Pb + o) = u;
        const float yr = sy1[row];
        ql0 += yr * p.x; ql1 += yr * p.y; ql2 += yr * p.z; ql3 += yr * p.w;
        float s = p.x * yv.x + p.y * yv.y + p.z * yv.z + p.w * yv.w;   // Piy1 partial
#pragma unroll
        for (int off = 32; off; off >>= 1) s += __shfl_down(s, off, 64);
        if (ln == 0) vec[(long)b * 768 + row] = s;
    }
    *(float4*)(qsh[wv] + col4) = make_float4(ql0, ql1, ql2, ql3);
    __syncthreads();
    // per-block q partial over l in [rs, rs+64): qpart[(b*4 + chunk)*256 + c]
    qpart[((long)blk) * DD + t] = qsh[0][t] + qsh[1][t] + qsh[2][t] + qsh[3][t];
}

// ---------------- L2: G-gemms (blocks 0..511, fp32-staged) + finalize (512..575) ------
__global__ __launch_bounds__(256)
void prep2(const float* __restrict__ Y1, const float* __restrict__ Y2,
           const float* __restrict__ y1g, const float* __restrict__ qpart,
           unsigned short* __restrict__ G1b, unsigned short* __restrict__ G21b,
           float* __restrict__ vec)
{
    __shared__ __align__(16) unsigned short As[128 * 32];
    __shared__ __align__(16) unsigned short Bs[128 * 32];
    const int blk = blockIdx.x, t = threadIdx.x;
    if (blk < 512) {
        const int quad = blk & 3, z = blk >> 2, sel = z >> 6, b = z & 63;
        const int i0 = (quad >> 1) * 128, j0 = (quad & 1) * 128;
        const float* Af = (sel ? Y2 : Y1) + (long)b * DD * MM;
        const float* Bf = Y1 + (long)b * DD * MM;
        unsigned short* Ob = (sel ? G21b : G1b) + (long)b * DD * DD;
        const int wv = t >> 6, ln = t & 63;
        const int lr = ln & 15, qd = ln >> 4;
        const int mh = (wv >> 1) * 64, nh = (wv & 1) * 64;
        const int srow = t >> 3, sk4 = (t & 7) * 4;
        f32x4 acc[4][4] = {};
        for (int kc = 0; kc < MM; kc += 32) {
            // stage fp32 -> bf16 into LDS ([row][k] 128x32)
#pragma unroll
            for (int i = 0; i < 4; ++i) {
                const int row = i * 32 + srow;
                float4 a = *(const float4*)(Af + (long)(i0 + row) * MM + kc + sk4);
                float4 c = *(const float4*)(Bf + (long)(j0 + row) * MM + kc + sk4);
                ushort4 ua, uc;
                ua.x = f2b(a.x); ua.y = f2b(a.y); ua.z = f2b(a.z); ua.w = f2b(a.w);
                uc.x = f2b(c.x); uc.y = f2b(c.y); uc.z = f2b(c.z); uc.w = f2b(c.w);
                *(ushort4*)(As + row * 32 + sk4) = ua;
                *(ushort4*)(Bs + row * 32 + sk4) = uc;
            }
            __syncthreads();
            short8 af[4], bfr[4];
#pragma unroll
            for (int mt = 0; mt < 4; ++mt)
                af[mt] = *(const short8*)(As + (mh + mt * 16 + lr) * 32 + qd * 8);
#pragma unroll
            for (int nt = 0; nt < 4; ++nt)
                bfr[nt] = *(const short8*)(Bs + (nh + nt * 16 + lr) * 32 + qd * 8);
#pragma unroll
            for (int mt = 0; mt < 4; ++mt)
#pragma unroll
                for (int nt = 0; nt < 4; ++nt)
                    acc[mt][nt] = __builtin_amdgcn_mfma_f32_16x16x32_bf16(
                        af[mt], bfr[nt], acc[mt][nt], 0, 0, 0);
            __syncthreads();
        }
#pragma unroll
        for (int mt = 0; mt < 4; ++mt)
#pragma unroll
            for (int nt = 0; nt < 4; ++nt) {
                const int gr0 = i0 + mh + mt * 16 + qd * 4;
                const int gc  = j0 + nh + nt * 16 + lr;
#pragma unroll
                for (int r = 0; r < 4; ++r)
                    Ob[(long)(gr0 + r) * DD + gc] = f2b(acc[mt][nt][r]);
            }
        return;
    }
    // finalize: q = sum of 4 partials; k = 1/(1 + y1.Piy1)
    const int b = blk - 512;
    float* vb = vec + (long)b * 768;
    const float* qp = qpart + (long)b * 4 * DD;
    vb[256 + t] = qp[t] + qp[DD + t] + qp[2 * DD + t] + qp[3 * DD + t];
    __shared__ float red[256];
    red[t] = vb[t] * y1g[b * DD + t];
    __syncthreads();
    for (int s = 128; s; s >>= 1) { if (t < s) red[t] += red[t + s]; __syncthreads(); }
    if (t == 0) vb[512] = 1.0f / (1.0f + red[0]);
}

// ---------------- L3: negE (0..255) / V' (256..511) + out2 tail (512..767) ------------
__global__ __launch_bounds__(256)
void gemmEV(const unsigned short* __restrict__ Pb, const unsigned short* __restrict__ G1b,
            const unsigned short* __restrict__ G21b,
            const float* __restrict__ P,
            const float* __restrict__ y1g, const float* __restrict__ y2g,
            const float* __restrict__ vec,
            unsigned short* __restrict__ Enb, unsigned short* __restrict__ Vpb,
            float* __restrict__ out2)
{
    __shared__ __align__(16) unsigned short As[128 * 32];
    __shared__ __align__(16) unsigned short Bs[128 * 32];
    __shared__ float qs[DD], s1[DD], s2[DD];
    const int blk = blockIdx.x, t = threadIdx.x;
    if (blk >= 512) {
        // out2 = P - k Piy1 q^T
        const int c = blk - 512, b = c >> 2, rs = (c & 3) * 64;
        const long base = (long)b * DD * DD;
        const float* vb = vec + (long)b * 768;
        const float kk = vb[512];
#pragma unroll 4
        for (int i = 0; i < 16; ++i) {
            const int idx = rs * DD + (i * 256 + t) * 4;
            const int row = idx >> 8, col = idx & 255;
            const float kPi = kk * vb[row];
            float4 p = *(const float4*)(P + base + idx);
            float4 q = *(const float4*)(vb + 256 + col);
            float4 rr;
            rr.x = p.x - kPi * q.x; rr.y = p.y - kPi * q.y;
            rr.z = p.z - kPi * q.z; rr.w = p.w - kPi * q.w;
            *(float4*)(out2 + base + idx) = rr;
        }
        return;
    }
    const int quad = blk & 3, z = blk >> 2, sel = z >> 6, b = z & 63;
    const int i0 = (quad >> 1) * 128, j0 = (quad & 1) * 128;
    const unsigned short* Ab = (sel ? G21b : Pb) + (long)b * DD * DD;
    const unsigned short* Bb = (sel ? Pb : G1b) + (long)b * DD * DD;
    unsigned short* Ob = (sel ? Vpb : Enb) + (long)b * DD * DD;
    const float* vb = vec + (long)b * 768;
    const int wv = t >> 6, ln = t & 63;
    const int lr = ln & 15, qd = ln >> 4;
    const int mh = (wv >> 1) * 64, nh = (wv & 1) * 64;
    const int srow = t >> 3, sk4 = (t & 7) * 4;

    qs[t] = vb[256 + t];
    s1[t] = y1g[b * DD + t];
    s2[t] = y2g[b * DD + t];

    f32x4 acc[4][4] = {};
    float dot[4] = {0.f, 0.f, 0.f, 0.f};   // sel0: G1q partial per nt; sel1: G21q per mt

    for (int kc = 0; kc < DD; kc += 32) {
        // stage bf16 [row][k] 128x32 via 8B copies
#pragma unroll
        for (int i = 0; i < 4; ++i) {
            const int row = i * 32 + srow;
            *(ushort4*)(As + row * 32 + sk4) =
                *(const ushort4*)(Ab + (long)(i0 + row) * DD + kc + sk4);
            *(ushort4*)(Bs + row * 32 + sk4) =
                *(const ushort4*)(Bb + (long)(j0 + row) * DD + kc + sk4);
        }
        __syncthreads();
        short8 af[4], bfr[4];
#pragma unroll
        for (int mt = 0; mt < 4; ++mt)
            af[mt] = *(const short8*)(As + (mh + mt * 16 + lr) * 32 + qd * 8);
#pragma unroll
        for (int nt = 0; nt < 4; ++nt)
            bfr[nt] = *(const short8*)(Bs + (nh + nt * 16 + lr) * 32 + qd * 8);
        const float4 qa = *(const float4*)(qs + kc + qd * 8);
        const float4 qb = *(const float4*)(qs + kc + qd * 8 + 4);
        const float qf[8] = {qa.x, qa.y, qa.z, qa.w, qb.x, qb.y, qb.z, qb.w};
        if (!sel) {
#pragma unroll
            for (int nt = 0; nt < 4; ++nt)
#pragma unroll
                for (int j = 0; j < 8; ++j)
                    dot[nt] += b2f((unsigned short)bfr[nt][j]) * qf[j];
        } else {
#pragma unroll
            for (int mt = 0; mt < 4; ++mt)
#pragma unroll
                for (int j = 0; j < 8; ++j)
                    dot[mt] += b2f((unsigned short)af[mt][j]) * qf[j];
        }
#pragma unroll
        for (int mt = 0; mt < 4; ++mt)
#pragma unroll
            for (int nt = 0; nt < 4; ++nt)
                acc[mt][nt] = __builtin_amdgcn_mfma_f32_16x16x32_bf16(
                    af[mt], bfr[nt], acc[mt][nt], 0, 0, 0);
        __syncthreads();
    }
#pragma unroll
    for (int i = 0; i < 4; ++i) {
        dot[i] += __shfl_xor(dot[i], 16, 64);
        dot[i] += __shfl_xor(dot[i], 32, 64);
    }
    const float kk = vb[512];
#pragma unroll
    for (int mt = 0; mt < 4; ++mt) {
#pragma unroll
        for (int nt = 0; nt < 4; ++nt) {
            const int gr0 = i0 + mh + mt * 16 + qd * 4;
            const int gc  = j0 + nh + nt * 16 + lr;
            if (!sel) {
                const float cw = s1[gc] - dot[nt];   // w[col]
#pragma unroll
                for (int r = 0; r < 4; ++r) {
                    const float rv = kk * s1[gr0 + r];
                    Ob[(long)(gr0 + r) * DD + gc] = f2b(-(acc[mt][nt][r] + rv * cw));
                }
            } else {
                const float cv = s1[gc];
#pragma unroll
                for (int r = 0; r < 4; ++r) {
                    const float uv = __shfl(dot[mt], qd * 4 + r, 64);   // u[row]
                    const float rv = kk * (s2[gr0 + r] - uv);
                    Ob[(long)(gr0 + r) * DD + gc] = f2b(acc[mt][nt][r] + rv * cv);
                }
            }
        }
    }
}

// ---------------- L4: persistent 10-step iterate, XOR-swizzled LDS ----------------
// grid (8,64): 32-row strips, 2 WGs/CU. Wave wv owns cols [wv*64, wv*64+64).
#define SWZ(row) (((row) ^ ((row) >> 3)) & 7)
__global__ __launch_bounds__(256, 2)
void iterk(const float* __restrict__ A_start, const unsigned short* __restrict__ Enb,
           const unsigned short* __restrict__ Vpb, float* __restrict__ out1)
{
    __shared__ __align__(16) unsigned short Ash[32 * 256];
    const int b = blockIdx.y, r0 = blockIdx.x * 32;
    const long base = (long)b * DD * DD;
    const float* Ab = A_start + base;
    const unsigned short* Eb = Enb + base;
    const unsigned short* Vb = Vpb + base;
    float* Ob = out1 + base;
    const int t = threadIdx.x, wv = t >> 6, ln = t & 63;
    const int lr = ln & 15, qd = ln >> 4;

    f32x4 acc[2][4], vv[2][4];
    short8 ef[4][8];

#pragma unroll
    for (int mt = 0; mt < 2; ++mt)
#pragma unroll
        for (int j = 0; j < 4; ++j) {
            const int col = wv * 64 + j * 16 + lr;
            const int rowb = r0 + mt * 16 + qd * 4;
#pragma unroll
            for (int r = 0; r < 4; ++r) {
                const long o = (long)(rowb + r) * DD + col;
                acc[mt][j][r] = Ab[o];
                vv[mt][j][r]  = b2f(Vb[o]);
            }
        }
#pragma unroll
    for (int j = 0; j < 4; ++j) {
        const int n = wv * 64 + j * 16 + lr;
#pragma unroll
        for (int kc = 0; kc < 8; ++kc)
            ef[j][kc] = *(const short8*)(Eb + (long)n * DD + kc * 32 + qd * 8);
    }

#pragma unroll 1
    for (int s = 0; s < 10; ++s) {
        const int cgb = wv * 8 + (lr >> 3), cb = lr & 7;
#pragma unroll
        for (int mt = 0; mt < 2; ++mt)
#pragma unroll
            for (int j = 0; j < 4; ++j) {
#pragma unroll
                for (int r = 0; r < 4; ++r) {
                    const int lrow = mt * 16 + qd * 4 + r;
                    const int cg = (cgb + j * 2) ^ SWZ(lrow);
                    Ash[lrow * 256 + cg * 8 + cb] = f2b(acc[mt][j][r]);
                }
                acc[mt][j] += vv[mt][j];
            }
        __syncthreads();
#pragma unroll
        for (int kc = 0; kc < 8; ++kc) {
            short8 af[2];
#pragma unroll
            for (int mt = 0; mt < 2; ++mt) {
                const int row = mt * 16 + lr;
                const int cg = (kc * 4 + qd) ^ SWZ(row);
                af[mt] = *(const short8*)(Ash + row * 256 + cg * 8);
            }
#pragma unroll
            for (int mt = 0; mt < 2; ++mt)
#pragma unroll
                for (int j = 0; j < 4; ++j)
                    acc[mt][j] = __builtin_amdgcn_mfma_f32_16x16x32_bf16(
                        af[mt], ef[j][kc], acc[mt][j], 0, 0, 0);
        }
        __syncthreads();
    }

#pragma unroll
    for (int mt = 0; mt < 2; ++mt)
#pragma unroll
        for (int j = 0; j < 4; ++j) {
            const int col = wv * 64 + j * 16 + lr;
            const int rowb = r0 + mt * 16 + qd * 4;
#pragma unroll
            for (int r = 0; r < 4; ++r)
                Ob[(long)(rowb + r) * DD + col] = acc[mt][j][r];
        }
}

extern "C" void kernel_launch(void* const* d_in, const int* in_sizes, int n_in,
                              void* d_out, int out_size, void* d_ws, size_t ws_size,
                              hipStream_t stream)
{
    const float* A_start = (const float*)d_in[0];
    const float* Y1      = (const float*)d_in[1];
    const float* Y2      = (const float*)d_in[2];
    const float* y1      = (const float*)d_in[3];
    const float* y2      = (const float*)d_in[4];
    const float* P       = (const float*)d_in[5];

    const long EL2 = (long)BSZ * DD * DD;   // 4,194,304

    float* out1 = (float*)d_out;
    float* out2 = out1 + EL2;

    char* w8 = (char*)d_ws;                          // ~41.5 MB used
    unsigned short* Pb    = (unsigned short*)(w8);                 // 8MB
    unsigned short* G1b   = (unsigned short*)(w8 + 8388608);       // 8MB
    unsigned short* G21b  = (unsigned short*)(w8 + 16777216);      // 8MB
    unsigned short* Enb   = (unsigned short*)(w8 + 25165824);      // 8MB
    unsigned short* Vpb   = (unsigned short*)(w8 + 33554432);      // 8MB
    float*          vec   = (float*)(w8 + 41943040);               // 64*768*4
    float*          qpart = (float*)(w8 + 42139648);               // 64*4*256*4

    const dim3 blk(256);

    prep1<<<256, blk, 0, stream>>>(P, y1, Pb, vec, qpart);
    prep2<<<576, blk, 0, stream>>>(Y1, Y2, y1, qpart, G1b, G21b, vec);
    gemmEV<<<768, blk, 0, stream>>>(Pb, G1b, G21b, P, y1, y2, vec, Enb, Vpb, out2);
    iterk<<<dim3(8, 64), blk, 0, stream>>>(A_start, Enb, Vpb, out1);
}